// Round 4
// baseline (2442.061 us; speedup 1.0000x reference)
//
#include <hip/hip_runtime.h>
#include <hip/hip_bf16.h>

typedef unsigned short u16;
typedef unsigned int u32;
typedef __attribute__((ext_vector_type(8))) short short8;
typedef __attribute__((ext_vector_type(4))) float f32x4;

struct TrueT  { static constexpr bool value = true;  };
struct FalseT { static constexpr bool value = false; };

// sizes: V=50000 E=256 H=512 T=50 C=5 B=128 S=512 FC1=500, 4H=2048
// ALL float tensors are f32 on device; x is int32; d_out is f32.

__device__ __forceinline__ float bf2f(u16 v){ union{u32 u; float f;} x; x.u = ((u32)v)<<16; return x.f; }
__device__ __forceinline__ u16 f2bf(float f){ union{float f; u32 u;} x; x.f = f; u32 r = ((x.u>>16)&1u) + 0x7FFFu; return (u16)((x.u + r)>>16); }
__device__ __forceinline__ float sigf(float x){ return 1.f/(1.f+__expf(-x)); }
__device__ __forceinline__ float tanh_f(float x){ return 2.f/(1.f+__expf(-2.f*x)) - 1.f; }

// ---- transpose+cast: W_h f32 [512][2048] -> WhT bf16 [2048][512]
//                      W_x f32 [256][2048] -> WxT bf16 [2048][256]
__global__ void k_prep(const float* __restrict__ Wh, const float* __restrict__ Wx,
                       u16* __restrict__ WhT, u16* __restrict__ WxT){
  __shared__ u16 tile[32][33];
  int b = blockIdx.x;
  const float* src; u16* dst; int K, kt, nt;
  if (b < 1024){ src = Wh; dst = WhT; K = 512; kt = b & 15; nt = b >> 4; }
  else { b -= 1024; src = Wx; dst = WxT; K = 256; kt = b & 7; nt = b >> 3; }
  int tx = threadIdx.x, ty = threadIdx.y;
  #pragma unroll
  for (int p = 0; p < 4; ++p){
    int r = p*8 + ty;
    tile[r][tx] = f2bf(src[(kt*32 + r)*2048 + nt*32 + tx]);
  }
  __syncthreads();
  #pragma unroll
  for (int p = 0; p < 4; ++p){
    int r = p*8 + ty;
    dst[(nt*32 + r)*K + kt*32 + tx] = tile[tx][r];
  }
}

// ---- tb[b][col] = bias[col] + sum_t topic[b][t]*W_t[t][col]   (all f32)
__global__ void k_topic(const float* __restrict__ topic, const float* __restrict__ Wt,
                        const float* __restrict__ bias, float* __restrict__ tb){
  int b = blockIdx.y;
  int col = blockIdx.x*256 + threadIdx.x;
  float acc = bias[col];
  #pragma unroll 5
  for (int t = 0; t < 50; ++t)
    acc += topic[b*50 + t] * Wt[t*2048 + col];
  tb[b*2048 + col] = acc;
}

// ---- init h ring buffer parity 0 (hi+lo split of f32 h0); zero flags + xcd map
__global__ void k_init(const float* __restrict__ h0, u16* __restrict__ hhi,
                       u16* __restrict__ hlo, u32* __restrict__ cnt, u32* __restrict__ xcdmap){
  if (blockIdx.x < 256){
    int i = blockIdx.x*256 + threadIdx.x;
    float v = h0[i];
    u16 hi = f2bf(v);
    hhi[i] = hi;
    hlo[i] = f2bf(v - bf2f(hi));
  } else {
    cnt[threadIdx.x] = 0;     // flag(g,w) = cnt[g*16+w]
    xcdmap[threadIdx.x] = 0;
  }
}

// ---- persistent LSTM: 256 wgs = 16 batch-groups (8 rows) x 16 col-wgs (32 h-cols)
// Fast path (group XCD-uniform, runtime-verified): h + flags via sc0 (per-XCD L2).
// Slow path: sc0 sc1 (LLC). Flags relaxed; release = vmcnt(0)+syncthreads before flag.
__global__ void __launch_bounds__(256, 1)
k_rnn(const int* __restrict__ x, const float* __restrict__ embed, const float* __restrict__ c0,
      const u16* __restrict__ WhT, const u16* __restrict__ WxT, const float* __restrict__ tb,
      u16* __restrict__ hhi, u16* __restrict__ hlo, float* __restrict__ hf,
      u32* cnt, u32* xcdmap)
{
  const int bx = blockIdx.x;
  const int g = bx & 15;      // batch group
  const int w = bx >> 4;      // h-column chunk [w*32, w*32+32)
  const int tid = threadIdx.x;
  const int v = tid >> 6;     // wave 0..3, owns N-tiles {2v, 2v+1}
  const int lane = tid & 63;
  const int l15 = lane & 15, l4 = lane >> 4;

  // ldsH granule-swizzled: logical 16B-granule gl of row r stored at granule gl^r
  __shared__ __align__(16) u16 ldsH[2][8][512];   // [hi/lo][row][col] 16KB
  __shared__ __align__(16) float ldsD[16][132];   // 8.4KB

  // ---- startup: stale-L2 invalidate, publish XCC_ID, global publish-barrier ----
  u32 myxcc;
  asm volatile("s_getreg_b32 %0, hwreg(HW_REG_XCC_ID)" : "=s"(myxcc));
  __builtin_amdgcn_fence(__ATOMIC_ACQUIRE, "agent");   // inv L1/L2 (stale-replay guard)
  __syncthreads();                                     // all waves of this wg fenced
  if (tid == 0){
    u32* mp = xcdmap + bx;
    const u32 val = myxcc | 0x100u;
    asm volatile("global_store_dword %0, %1, off sc0 sc1" :: "v"(mp), "v"(val) : "memory");
  }

  // epilogue cell: thread owns (row er, h-col ehc); c stays in this register
  const int er = tid >> 5, ehc = tid & 31;
  const int eb = g*8 + er;
  const int ecol = w*32 + ehc;
  float c_val = c0[eb*512 + ecol];
  const float tb0 = tb[eb*2048 +    0 + ecol];
  const float tb1 = tb[eb*2048 +  512 + ecol];
  const float tb2 = tb[eb*2048 + 1024 + ecol];
  const float tb3 = tb[eb*2048 + 1536 + ecol];

  // preload all B fragments into registers (step-invariant).
  // local col cl = hc*4+q  ->  global gate col = q*512 + w*32 + hc  (q: i,f,g,o)
  short8 b2[2][16], b1[2][8];
  #pragma unroll
  for (int j = 0; j < 2; ++j){
    const int cl = (2*v + j)*16 + l15;
    const int cg = (cl & 3)*512 + w*32 + (cl >> 2);
    #pragma unroll
    for (int kt = 0; kt < 16; ++kt)
      b2[j][kt] = *(const short8*)(WhT + cg*512 + kt*32 + l4*8);
    #pragma unroll
    for (int kt = 0; kt < 8; ++kt)
      b1[j][kt] = *(const short8*)(WxT + cg*256 + kt*32 + l4*8);
  }

  const int ar = l15 & 7;        // A rows 8..15 duplicate 0..7
  const int ab = g*8 + ar;
  const int xbase = ab*512;

  auto ld_emb = [&](int t, short8 (&a)[8]){
    const int idx = x[xbase + t];
    const float* ep = embed + (u32)idx*256 + l4*8;
    #pragma unroll
    for (int kt = 0; kt < 8; ++kt){
      float4 f0 = *(const float4*)(ep + kt*32);
      float4 f1 = *(const float4*)(ep + kt*32 + 4);
      union { short8 s; u32 u[4]; } pk;
      asm("v_cvt_pk_bf16_f32 %0, %1, %2" : "=v"(pk.u[0]) : "v"(f0.x), "v"(f0.y));
      asm("v_cvt_pk_bf16_f32 %0, %1, %2" : "=v"(pk.u[1]) : "v"(f0.z), "v"(f0.w));
      asm("v_cvt_pk_bf16_f32 %0, %1, %2" : "=v"(pk.u[2]) : "v"(f1.x), "v"(f1.y));
      asm("v_cvt_pk_bf16_f32 %0, %1, %2" : "=v"(pk.u[3]) : "v"(f1.z), "v"(f1.w));
      a[kt] = pk.s;
    }
  };

  short8 a1A[8], a1B[8];
  ld_emb(0, a1A);

  // wait until ALL 256 wgs have published (=> all L2 invalidates chip-wide done
  // before any sc0 protocol traffic can be cached anywhere)
  {
    bool all_pub;
    const u32* mp = xcdmap + lane*4;
    do {
      union { f32x4 v4; u32 u[4]; } m;
      asm volatile("global_load_dwordx4 %0, %1, off sc0 sc1\n\ts_waitcnt vmcnt(0)"
                   : "=v"(m.v4) : "v"(mp) : "memory");
      all_pub = __all((int)((m.u[0] & m.u[1] & m.u[2] & m.u[3] & 0x100u) != 0)) != 0;
    } while (!all_pub);
  }
  bool fast;
  {
    const u32* mp = xcdmap + (g + (lane & 15)*16);   // my group's 16 members
    u32 mv;
    asm volatile("global_load_dword %0, %1, off sc0 sc1\n\ts_waitcnt vmcnt(0)"
                 : "=v"(mv) : "v"(mp) : "memory");
    fast = __all((int)(lane >= 16 || (mv & 0xFFu) == myxcc)) != 0;
  }
  __syncthreads();

  const int sr = tid >> 5;            // staging row
  const int g0 = (tid & 31) * 2;      // staging logical granule pair

  auto step = [&](auto FC, int t, short8 (&a1c)[8], short8 (&a1n)[8]){
    constexpr bool F = decltype(FC)::value;
    f32x4 acc0a = {0.f,0.f,0.f,0.f}, acc0b = {0.f,0.f,0.f,0.f};
    f32x4 acc1a = {0.f,0.f,0.f,0.f}, acc1b = {0.f,0.f,0.f,0.f};
    // x-embedding contribution — independent of h_t, hides inside the flag wait
    #pragma unroll
    for (int kt = 0; kt < 8; ++kt){
      acc0a = __builtin_amdgcn_mfma_f32_16x16x32_bf16(a1c[kt], b1[0][kt], acc0a, 0, 0, 0);
      acc1a = __builtin_amdgcn_mfma_f32_16x16x32_bf16(a1c[kt], b1[1][kt], acc1a, 0, 0, 0);
    }
    // prefetch next step's embedding rows
    ld_emb((t < 511) ? t + 1 : 511, a1n);
    // wait until all 16 wgs of this group have published h_t (one 64B line)
    if (t > 0){
      const u32 tgt = (u32)t;
      const u32* fp = cnt + (g*16 + (lane & 15));
      bool ok;
      do {
        u32 cv;
        if constexpr (F)
          asm volatile("global_load_dword %0, %1, off sc0\n\ts_waitcnt vmcnt(0)"
                       : "=v"(cv) : "v"(fp) : "memory");
        else
          asm volatile("global_load_dword %0, %1, off sc0 sc1\n\ts_waitcnt vmcnt(0)"
                       : "=v"(cv) : "v"(fp) : "memory");
        ok = __all((int)(lane >= 16 || cv >= tgt)) != 0;
      } while (!ok);
    }
    // cooperative stage of group's h (8 rows x 512, hi+lo)
    {
      const u16* sh = hhi + (t & 1)*65536 + g*4096 + tid*16;
      const u16* sl = hlo + (t & 1)*65536 + g*4096 + tid*16;
      f32x4 h0, h1, q0, q1;
      if constexpr (F){
        asm volatile("global_load_dwordx4 %0, %2, off sc0\n\t"
                     "global_load_dwordx4 %1, %3, off sc0"
                     : "=v"(h0), "=v"(h1) : "v"(sh), "v"(sh + 8));
        asm volatile("global_load_dwordx4 %0, %2, off sc0\n\t"
                     "global_load_dwordx4 %1, %3, off sc0"
                     : "=v"(q0), "=v"(q1) : "v"(sl), "v"(sl + 8));
      } else {
        asm volatile("global_load_dwordx4 %0, %2, off sc0 sc1\n\t"
                     "global_load_dwordx4 %1, %3, off sc0 sc1"
                     : "=v"(h0), "=v"(h1) : "v"(sh), "v"(sh + 8));
        asm volatile("global_load_dwordx4 %0, %2, off sc0 sc1\n\t"
                     "global_load_dwordx4 %1, %3, off sc0 sc1"
                     : "=v"(q0), "=v"(q1) : "v"(sl), "v"(sl + 8));
      }
      asm volatile("s_waitcnt vmcnt(0)" ::: "memory");
      asm volatile("" : "+v"(h0), "+v"(h1), "+v"(q0), "+v"(q1));  // pin uses after waitcnt
      // swizzled LDS writes: granule gl of row r at gl^r  (<=2-way banks: free)
      *(f32x4*)&ldsH[0][sr][((g0    ) ^ sr)*8] = h0;
      *(f32x4*)&ldsH[0][sr][((g0 + 1) ^ sr)*8] = h1;
      *(f32x4*)&ldsH[1][sr][((g0    ) ^ sr)*8] = q0;
      *(f32x4*)&ldsH[1][sr][((g0 + 1) ^ sr)*8] = q1;
    }
    __syncthreads();
    // recurrent MFMAs from LDS (hi+lo split; swizzled reads conflict-free)
    #pragma unroll
    for (int kt = 0; kt < 16; ++kt){
      const int go = ((kt*4 + l4) ^ ar)*8;
      short8 ah = *(const short8*)&ldsH[0][ar][go];
      short8 al = *(const short8*)&ldsH[1][ar][go];
      acc0a = __builtin_amdgcn_mfma_f32_16x16x32_bf16(ah, b2[0][kt], acc0a, 0, 0, 0);
      acc0b = __builtin_amdgcn_mfma_f32_16x16x32_bf16(al, b2[0][kt], acc0b, 0, 0, 0);
      acc1a = __builtin_amdgcn_mfma_f32_16x16x32_bf16(ah, b2[1][kt], acc1a, 0, 0, 0);
      acc1b = __builtin_amdgcn_mfma_f32_16x16x32_bf16(al, b2[1][kt], acc1b, 0, 0, 0);
    }
    const f32x4 acc0 = acc0a + acc0b;
    const f32x4 acc1 = acc1a + acc1b;
    // D fragments -> LDS (C/D layout: col=lane&15, row=(lane>>4)*4+reg)
    #pragma unroll
    for (int jj = 0; jj < 4; ++jj){
      ldsD[l4*4 + jj][(2*v + 0)*16 + l15] = acc0[jj];
      ldsD[l4*4 + jj][(2*v + 1)*16 + l15] = acc1[jj];
    }
    __syncthreads();
    // gates: local col hc*4+q holds gate q of cell (er, ehc); one b128 read
    const f32x4 pre = *(const f32x4*)&ldsD[er][ehc*4];
    const float iv = sigf(pre[0] + tb0);
    const float fv = sigf(pre[1] + tb1);
    const float gv = tanh_f(pre[2] + tb2);
    const float ov = sigf(pre[3] + tb3);
    c_val = fv*c_val + iv*gv;
    const float hval = ov*tanh_f(c_val);
    if (t < 511){
      const u16 hi = f2bf(hval);
      const u16 lo = f2bf(hval - bf2f(hi));
      const int np_ = (t + 1) & 1;
      u16* dh = hhi + np_*65536 + eb*512 + ecol;
      u16* dl = hlo + np_*65536 + eb*512 + ecol;
      if constexpr (F){
        asm volatile("global_store_short %0, %1, off sc0" :: "v"(dh), "v"((u32)hi) : "memory");
        asm volatile("global_store_short %0, %1, off sc0" :: "v"(dl), "v"((u32)lo) : "memory");
      } else {
        asm volatile("global_store_short %0, %1, off sc0 sc1" :: "v"(dh), "v"((u32)hi) : "memory");
        asm volatile("global_store_short %0, %1, off sc0 sc1" :: "v"(dl), "v"((u32)lo) : "memory");
      }
    } else {
      hf[eb*512 + ecol] = hval;
    }
    asm volatile("s_waitcnt vmcnt(0)" ::: "memory");  // h stores acked at coherence point
    __syncthreads();                                   // all waves acked
    if (tid == 0 && t < 511){
      const u32 fv_ = (u32)(t + 1);
      u32* fp = cnt + (g*16 + w);
      if constexpr (F)
        asm volatile("global_store_dword %0, %1, off sc0" :: "v"(fp), "v"(fv_) : "memory");
      else
        asm volatile("global_store_dword %0, %1, off sc0 sc1" :: "v"(fp), "v"(fv_) : "memory");
    }
  };

  if (fast){
    for (int t = 0; t < 512; t += 2){
      step(TrueT{},  t,     a1A, a1B);
      step(TrueT{},  t + 1, a1B, a1A);
    }
  } else {
    for (int t = 0; t < 512; t += 2){
      step(FalseT{}, t,     a1A, a1B);
      step(FalseT{}, t + 1, a1B, a1A);
    }
  }
}

// ---- head: hid = h @ fc1_w^T + fc1_b   (f32)
__global__ void k_head1(const float* __restrict__ hf, const float* __restrict__ w1,
                        const float* __restrict__ b1v, float* __restrict__ hid){
  int b = blockIdx.y;
  int j = blockIdx.x*256 + threadIdx.x;
  if (j >= 500) return;
  float acc = b1v[j];
  const float* hr = hf + b*512;
  const float* wr = w1 + j*512;
  for (int k = 0; k < 512; ++k) acc += hr[k]*wr[k];
  hid[b*500 + j] = acc;
}

// ---- head: logits = hid @ fc2_w^T + fc2_b   (f32 out)
__global__ void k_head2(const float* __restrict__ hid, const float* __restrict__ w2,
                        const float* __restrict__ b2v, float* __restrict__ out){
  int o = blockIdx.x*256 + threadIdx.x;
  if (o >= 640) return;
  int b = o / 5, cls = o % 5;
  float acc = b2v[cls];
  const float* hr = hid + b*500;
  const float* wr = w2 + cls*500;
  for (int j = 0; j < 500; ++j) acc += hr[j]*wr[j];
  out[o] = acc;
}

extern "C" void kernel_launch(void* const* d_in, const int* in_sizes, int n_in,
                              void* d_out, int out_size, void* d_ws, size_t ws_size,
                              hipStream_t stream) {
  const int*   x     = (const int*)d_in[0];
  const float* topic = (const float*)d_in[1];
  const float* h0    = (const float*)d_in[2];
  const float* c0    = (const float*)d_in[3];
  const float* embed = (const float*)d_in[4];
  const float* Wx    = (const float*)d_in[5];
  const float* Wt    = (const float*)d_in[6];
  const float* Wh    = (const float*)d_in[7];
  const float* bias  = (const float*)d_in[8];
  const float* fc1w  = (const float*)d_in[9];
  const float* fc1b  = (const float*)d_in[10];
  const float* fc2w  = (const float*)d_in[11];
  const float* fc2b  = (const float*)d_in[12];

  char* ws = (char*)d_ws;              // total ~5.27 MB
  u16*   WhT = (u16*)(ws + 0);         // 2048*512*2  = 2097152
  u16*   WxT = (u16*)(ws + 2097152);   // 2048*256*2  = 1048576
  float* tb  = (float*)(ws + 3145728); // 128*2048*4  = 1048576
  u16*   hhi = (u16*)(ws + 4194304);   // 2*128*512*2 = 262144
  u16*   hlo = (u16*)(ws + 4456448);   // 262144
  float* hf  = (float*)(ws + 4718592); // 128*512*4   = 262144
  float* hid = (float*)(ws + 4980736); // 128*500*4   = 256000
  u32*   cnt = (u32*)(ws + 5236736);   // 256*4 (group-major, 64B/group)
  u32*   xcd = (u32*)(ws + 5237760);   // 256*4

  k_prep<<<dim3(1536), dim3(32, 8), 0, stream>>>(Wh, Wx, WhT, WxT);
  k_topic<<<dim3(8, 128), dim3(256), 0, stream>>>(topic, Wt, bias, tb);
  k_init<<<dim3(257), dim3(256), 0, stream>>>(h0, hhi, hlo, cnt, xcd);

  // 256 wgs, <=25KB LDS, 256 threads -> all co-resident (capacity >> 1 wg/CU)
  k_rnn<<<dim3(256), dim3(256), 0, stream>>>(x, embed, c0, WhT, WxT, tb, hhi, hlo, hf, cnt, xcd);

  k_head1<<<dim3(2, 128), dim3(256), 0, stream>>>(hf, fc1w, fc1b, hid);
  k_head2<<<dim3(3), dim3(256), 0, stream>>>(hid, fc2w, fc2b, (float*)d_out);
}

// Round 6
// 1916.684 us; speedup vs baseline: 1.2741x; 1.2741x over previous
//
#include <hip/hip_runtime.h>
#include <hip/hip_bf16.h>

typedef unsigned short u16;
typedef unsigned int u32;
typedef __attribute__((ext_vector_type(8))) short short8;
typedef __attribute__((ext_vector_type(4))) float f32x4;

struct TrueT  { static constexpr bool value = true;  };
struct FalseT { static constexpr bool value = false; };

// sizes: V=50000 E=256 H=512 T=50 C=5 B=128 S=512 FC1=500, 4H=2048
// ALL float tensors are f32 on device; x is int32; d_out is f32.

__device__ __forceinline__ float bf2f(u16 v){ union{u32 u; float f;} x; x.u = ((u32)v)<<16; return x.f; }
__device__ __forceinline__ u16 f2bf(float f){ union{float f; u32 u;} x; x.f = f; u32 r = ((x.u>>16)&1u) + 0x7FFFu; return (u16)((x.u + r)>>16); }
__device__ __forceinline__ float sigf(float x){ return 1.f/(1.f+__expf(-x)); }
__device__ __forceinline__ float tanh_f(float x){ return 2.f/(1.f+__expf(-2.f*x)) - 1.f; }

#define POLL_GUARD (1u<<21)   // watchdog: converts any deadlock into wrong-answer, not timeout

// ---- transpose+cast: W_h f32 [512][2048] -> WhT bf16 [2048][512]
//                      W_x f32 [256][2048] -> WxT bf16 [2048][256]
__global__ void k_prep(const float* __restrict__ Wh, const float* __restrict__ Wx,
                       u16* __restrict__ WhT, u16* __restrict__ WxT){
  __shared__ u16 tile[32][33];
  int b = blockIdx.x;
  const float* src; u16* dst; int K, kt, nt;
  if (b < 1024){ src = Wh; dst = WhT; K = 512; kt = b & 15; nt = b >> 4; }
  else { b -= 1024; src = Wx; dst = WxT; K = 256; kt = b & 7; nt = b >> 3; }
  int tx = threadIdx.x, ty = threadIdx.y;
  #pragma unroll
  for (int p = 0; p < 4; ++p){
    int r = p*8 + ty;
    tile[r][tx] = f2bf(src[(kt*32 + r)*2048 + nt*32 + tx]);
  }
  __syncthreads();
  #pragma unroll
  for (int p = 0; p < 4; ++p){
    int r = p*8 + ty;
    dst[(nt*32 + r)*K + kt*32 + tx] = tile[tx][r];
  }
}

// ---- tb[b][col] = bias[col] + sum_t topic[b][t]*W_t[t][col]   (all f32)
__global__ void k_topic(const float* __restrict__ topic, const float* __restrict__ Wt,
                        const float* __restrict__ bias, float* __restrict__ tb){
  int b = blockIdx.y;
  int col = blockIdx.x*256 + threadIdx.x;
  float acc = bias[col];
  #pragma unroll 5
  for (int t = 0; t < 50; ++t)
    acc += topic[b*50 + t] * Wt[t*2048 + col];
  tb[b*2048 + col] = acc;
}

// ---- init h ring buffer parity 0 (hi+lo split of f32 h0); zero flags + xcd map
__global__ void k_init(const float* __restrict__ h0, u16* __restrict__ hhi,
                       u16* __restrict__ hlo, u32* __restrict__ cnt, u32* __restrict__ xcdmap){
  if (blockIdx.x < 256){
    int i = blockIdx.x*256 + threadIdx.x;
    float v = h0[i];
    u16 hi = f2bf(v);
    hhi[i] = hi;
    hlo[i] = f2bf(v - bf2f(hi));
  } else {
    cnt[threadIdx.x] = 0;     // flag(g,w) = cnt[g*16+w]
    xcdmap[threadIdx.x] = 0;
  }
}

// ---- persistent LSTM: 256 wgs = 16 batch-groups (8 rows) x 16 col-wgs (32 h-cols)
// Plane-in-M: A rows 0..7 = hi(h), rows 8..15 = lo(h); epilogue sums D[r]+D[r+8].
// Fast path (group XCD-uniform, runtime-verified): h + flags via sc0 (per-XCD L2).
__global__ void __launch_bounds__(256, 1)
k_rnn(const int* __restrict__ x, const float* __restrict__ embed, const float* __restrict__ c0,
      const u16* __restrict__ WhT, const u16* __restrict__ WxT, const float* __restrict__ tb,
      u16* __restrict__ hhi, u16* __restrict__ hlo, float* __restrict__ hf,
      u32* cnt, u32* xcdmap)
{
  const int bx = blockIdx.x;
  const int g = bx & 15;      // batch group
  const int w = bx >> 4;      // h-column chunk [w*32, w*32+32)
  const int tid = threadIdx.x;
  const int v = tid >> 6;     // wave 0..3, owns N-tiles {2v, 2v+1}
  const int lane = tid & 63;
  const int l15 = lane & 15, l4 = lane >> 4;
  const int arr = l15 & 7;    // A row within 8
  const int pl  = l15 >> 3;   // 0 = hi plane, 1 = lo plane

  __shared__ __align__(16) u16 ldsH[2][8][512];   // [plane][row][col] 16KB, XOR-swizzled
  __shared__ __align__(16) float ldsD[16][132];   // 8.4KB
  __shared__ int ldsX[8][512];                    // group's x indices, 16KB

  // ---- startup: stale-L2 invalidate, publish XCC_ID ----
  u32 myxcc;
  asm volatile("s_getreg_b32 %0, hwreg(HW_REG_XCC_ID)" : "=s"(myxcc));
  __builtin_amdgcn_fence(__ATOMIC_ACQUIRE, "agent");
  __syncthreads();
  if (tid == 0){
    u32* mp = xcdmap + bx;
    const u32 val = myxcc | 0x100u;
    asm volatile("global_store_dword %0, %1, off sc0 sc1" :: "v"(mp), "v"(val) : "memory");
  }

  // epilogue cell: thread owns (row er, h-col ehc)
  const int er = tid >> 5, ehc = tid & 31;
  const int eb = g*8 + er;
  const int ecol = w*32 + ehc;
  float c_val = c0[eb*512 + ecol];
  const float tb0 = tb[eb*2048 +    0 + ecol];
  const float tb1 = tb[eb*2048 +  512 + ecol];
  const float tb2 = tb[eb*2048 + 1024 + ecol];
  const float tb3 = tb[eb*2048 + 1536 + ecol];

  // preload B fragments (step-invariant); local col cl=hc*4+q -> gate col q*512+w*32+hc
  short8 b2[2][16], b1[2][8];
  #pragma unroll
  for (int j = 0; j < 2; ++j){
    const int cl = (2*v + j)*16 + l15;
    const int cg = (cl & 3)*512 + w*32 + (cl >> 2);
    #pragma unroll
    for (int kt = 0; kt < 16; ++kt)
      b2[j][kt] = *(const short8*)(WhT + cg*512 + kt*32 + l4*8);
    #pragma unroll
    for (int kt = 0; kt < 8; ++kt)
      b1[j][kt] = *(const short8*)(WxT + cg*256 + kt*32 + l4*8);
  }

  // stage this group's x block into LDS (8 rows x 512)
  {
    const int4* src = (const int4*)(x + g*4096);
    int4* dst = (int4*)&ldsX[0][0];
    #pragma unroll
    for (int i = 0; i < 4; ++i) dst[tid + 256*i] = src[tid + 256*i];
  }
  __syncthreads();

  const short8 z8 = {0,0,0,0,0,0,0,0};
  short8 a1A[8], a1B[8];
  {
    const int idx0 = ldsX[arr][0];
    const float* ep = embed + (u32)idx0*256 + l4*8;
    #pragma unroll
    for (int kt = 0; kt < 8; ++kt){
      float4 f0 = *(const float4*)(ep + kt*32);
      float4 f1 = *(const float4*)(ep + kt*32 + 4);
      union { short8 s; u32 u[4]; } pk;
      asm("v_cvt_pk_bf16_f32 %0, %1, %2" : "=v"(pk.u[0]) : "v"(f0.x), "v"(f0.y));
      asm("v_cvt_pk_bf16_f32 %0, %1, %2" : "=v"(pk.u[1]) : "v"(f0.z), "v"(f0.w));
      asm("v_cvt_pk_bf16_f32 %0, %1, %2" : "=v"(pk.u[2]) : "v"(f1.x), "v"(f1.y));
      asm("v_cvt_pk_bf16_f32 %0, %1, %2" : "=v"(pk.u[3]) : "v"(f1.z), "v"(f1.w));
      a1A[kt] = (l15 < 8) ? pk.s : z8;   // rows 8..15: zero x-contribution
    }
  }

  // wait until ALL 256 wgs have published (all startup invalidates done chip-wide)
  {
    bool all_pub; u32 guard = 0;
    const u32* mp = xcdmap + lane*4;
    do {
      union { f32x4 v4; u32 u[4]; } m;
      asm volatile("global_load_dwordx4 %0, %1, off sc0 sc1\n\ts_waitcnt vmcnt(0)"
                   : "=v"(m.v4) : "v"(mp) : "memory");
      all_pub = __all((int)((m.u[0] & m.u[1] & m.u[2] & m.u[3] & 0x100u) != 0)) != 0;
    } while (!all_pub && ++guard < POLL_GUARD);
  }
  bool fast;
  {
    const u32* mp = xcdmap + (g + (lane & 15)*16);
    u32 mv;
    asm volatile("global_load_dword %0, %1, off sc0 sc1\n\ts_waitcnt vmcnt(0)"
                 : "=v"(mv) : "v"(mp) : "memory");
    fast = __all((int)(lane >= 16 || (mv & 0xFFu) == myxcc)) != 0;
  }
  __syncthreads();

  // staging constants: thread stages 32B of row sr, logical granules (2*j31, 2*j31+1)
  const int sr = tid >> 5;
  const int j31 = tid & 31;
  const int ph0 = (2*j31) ^ (((2*j31) >> 3) ^ sr);   // balanced bijective XOR swizzle
  const int ph1 = ph0 ^ 1;

  auto step = [&](auto FC, int t, short8 (&a1c)[8], short8 (&a1n)[8]){
    constexpr bool F = decltype(FC)::value;
    // P0: ISSUE next-step embedding loads (retired by the poll's vmcnt(0), i.e.
    // their L3 latency overlaps the flag wait we must pay anyway)
    const int tn = (t < 511) ? t + 1 : 511;
    const int idxn = ldsX[arr][tn];
    const float* ep = embed + (u32)idxn*256 + l4*8;
    f32x4 e[16];
    #pragma unroll
    for (int kt = 0; kt < 8; ++kt){
      asm volatile("global_load_dwordx4 %0, %2, off\n\t"
                   "global_load_dwordx4 %1, %3, off"
                   : "=v"(e[2*kt]), "=v"(e[2*kt+1])
                   : "v"(ep + kt*32), "v"(ep + kt*32 + 4));
    }
    // A: x-phase MFMAs (register-only)
    f32x4 aX0 = {0.f,0.f,0.f,0.f}, aX1 = {0.f,0.f,0.f,0.f};
    #pragma unroll
    for (int kt = 0; kt < 8; ++kt){
      aX0 = __builtin_amdgcn_mfma_f32_16x16x32_bf16(a1c[kt], b1[0][kt], aX0, 0, 0, 0);
      aX1 = __builtin_amdgcn_mfma_f32_16x16x32_bf16(a1c[kt], b1[1][kt], aX1, 0, 0, 0);
    }
    // B: poll flags (R4-proven protocol, + watchdog)
    if (t > 0){
      const u32 tgt = (u32)t;
      const u32* fp = cnt + (g*16 + (lane & 15));
      bool ok; u32 guard = 0;
      do {
        u32 cv;
        if constexpr (F)
          asm volatile("global_load_dword %0, %1, off sc0\n\ts_waitcnt vmcnt(0)"
                       : "=v"(cv) : "v"(fp) : "memory");
        else
          asm volatile("global_load_dword %0, %1, off sc0 sc1\n\ts_waitcnt vmcnt(0)"
                       : "=v"(cv) : "v"(fp) : "memory");
        ok = __all((int)(lane >= 16 || cv >= tgt)) != 0;
      } while (!ok && ++guard < POLL_GUARD);
    }
    // C: staged h loads + vmcnt(0) + swizzled LDS writes (R4-proven)
    {
      const u16* sh = hhi + (t & 1)*65536 + g*4096 + tid*16;
      const u16* sl = hlo + (t & 1)*65536 + g*4096 + tid*16;
      f32x4 h0, h1, q0, q1;
      if constexpr (F){
        asm volatile("global_load_dwordx4 %0, %2, off sc0\n\t"
                     "global_load_dwordx4 %1, %3, off sc0"
                     : "=v"(h0), "=v"(h1) : "v"(sh), "v"(sh + 8));
        asm volatile("global_load_dwordx4 %0, %2, off sc0\n\t"
                     "global_load_dwordx4 %1, %3, off sc0"
                     : "=v"(q0), "=v"(q1) : "v"(sl), "v"(sl + 8));
      } else {
        asm volatile("global_load_dwordx4 %0, %2, off sc0 sc1\n\t"
                     "global_load_dwordx4 %1, %3, off sc0 sc1"
                     : "=v"(h0), "=v"(h1) : "v"(sh), "v"(sh + 8));
        asm volatile("global_load_dwordx4 %0, %2, off sc0 sc1\n\t"
                     "global_load_dwordx4 %1, %3, off sc0 sc1"
                     : "=v"(q0), "=v"(q1) : "v"(sl), "v"(sl + 8));
      }
      asm volatile("s_waitcnt vmcnt(0)" ::: "memory");
      asm volatile("" : "+v"(h0), "+v"(h1), "+v"(q0), "+v"(q1));
      *(f32x4*)&ldsH[0][sr][ph0*8] = h0;
      *(f32x4*)&ldsH[0][sr][ph1*8] = h1;
      *(f32x4*)&ldsH[1][sr][ph0*8] = q0;
      *(f32x4*)&ldsH[1][sr][ph1*8] = q1;
    }
    __syncthreads();
    // G: h-phase MFMAs; A rows 0..7 read hi plane, rows 8..15 lo plane (dedup)
    f32x4 c0a = {0.f,0.f,0.f,0.f}, c0b = {0.f,0.f,0.f,0.f};
    f32x4 c1a = {0.f,0.f,0.f,0.f}, c1b = {0.f,0.f,0.f,0.f};
    #pragma unroll
    for (int kt = 0; kt < 8; ++kt){
      const int gg = kt*4 + l4;
      const int ph = gg ^ ((gg >> 3) ^ arr);
      short8 ah = *(const short8*)&ldsH[pl][arr][ph*8];
      c0a = __builtin_amdgcn_mfma_f32_16x16x32_bf16(ah, b2[0][kt], c0a, 0, 0, 0);
      c1a = __builtin_amdgcn_mfma_f32_16x16x32_bf16(ah, b2[1][kt], c1a, 0, 0, 0);
    }
    #pragma unroll
    for (int kt = 8; kt < 16; ++kt){
      const int gg = kt*4 + l4;
      const int ph = gg ^ ((gg >> 3) ^ arr);
      short8 ah = *(const short8*)&ldsH[pl][arr][ph*8];
      c0b = __builtin_amdgcn_mfma_f32_16x16x32_bf16(ah, b2[0][kt], c0b, 0, 0, 0);
      c1b = __builtin_amdgcn_mfma_f32_16x16x32_bf16(ah, b2[1][kt], c1b, 0, 0, 0);
    }
    const f32x4 acc0 = (aX0 + c0a) + c0b;
    const f32x4 acc1 = (aX1 + c1a) + c1b;
    // H: D -> LDS (C/D layout: col=lane&15, row=(lane>>4)*4+reg), then gates
    #pragma unroll
    for (int jj = 0; jj < 4; ++jj){
      ldsD[l4*4 + jj][(2*v + 0)*16 + l15] = acc0[jj];
      ldsD[l4*4 + jj][(2*v + 1)*16 + l15] = acc1[jj];
    }
    __syncthreads();
    const f32x4 pa = *(const f32x4*)&ldsD[er][ehc*4];       // hi rows (+x)
    const f32x4 pb = *(const f32x4*)&ldsD[er + 8][ehc*4];   // lo rows
    const float iv = sigf(pa[0] + pb[0] + tb0);
    const float fv = sigf(pa[1] + pb[1] + tb1);
    const float gv = tanh_f(pa[2] + pb[2] + tb2);
    const float ov = sigf(pa[3] + pb[3] + tb3);
    c_val = fv*c_val + iv*gv;
    const float hval = ov*tanh_f(c_val);
    if (t < 511){
      const u16 hi = f2bf(hval);
      const u16 lo = f2bf(hval - bf2f(hi));
      const int np_ = (t + 1) & 1;
      u16* dh = hhi + np_*65536 + eb*512 + ecol;
      u16* dl = hlo + np_*65536 + eb*512 + ecol;
      if constexpr (F){
        asm volatile("global_store_short %0, %1, off sc0" :: "v"(dh), "v"((u32)hi) : "memory");
        asm volatile("global_store_short %0, %1, off sc0" :: "v"(dl), "v"((u32)lo) : "memory");
      } else {
        asm volatile("global_store_short %0, %1, off sc0 sc1" :: "v"(dh), "v"((u32)hi) : "memory");
        asm volatile("global_store_short %0, %1, off sc0 sc1" :: "v"(dl), "v"((u32)lo) : "memory");
      }
    } else {
      hf[eb*512 + ecol] = hval;
    }
    // I: drain (h stores acked at coherence point; e[] loads long since landed)
    asm volatile("s_waitcnt vmcnt(0)" ::: "memory");
    // K: all waves acked -> publish flag ASAP
    __syncthreads();
    if (tid == 0 && t < 511){
      const u32 fv_ = (u32)(t + 1);
      u32* fp = cnt + (g*16 + w);
      if constexpr (F)
        asm volatile("global_store_dword %0, %1, off sc0" :: "v"(fp), "v"(fv_) : "memory");
      else
        asm volatile("global_store_dword %0, %1, off sc0 sc1" :: "v"(fp), "v"(fv_) : "memory");
    }
    // J: convert next-step embedding (values valid: vmcnt(0) at C/I preceded)
    #pragma unroll
    for (int kt = 0; kt < 8; ++kt){
      union { short8 s; u32 u[4]; } pk;
      asm volatile("v_cvt_pk_bf16_f32 %0, %1, %2" : "=v"(pk.u[0]) : "v"(e[2*kt][0]),   "v"(e[2*kt][1]));
      asm volatile("v_cvt_pk_bf16_f32 %0, %1, %2" : "=v"(pk.u[1]) : "v"(e[2*kt][2]),   "v"(e[2*kt][3]));
      asm volatile("v_cvt_pk_bf16_f32 %0, %1, %2" : "=v"(pk.u[2]) : "v"(e[2*kt+1][0]), "v"(e[2*kt+1][1]));
      asm volatile("v_cvt_pk_bf16_f32 %0, %1, %2" : "=v"(pk.u[3]) : "v"(e[2*kt+1][2]), "v"(e[2*kt+1][3]));
      a1n[kt] = (l15 < 8) ? pk.s : z8;
    }
  };

  if (fast){
    for (int t = 0; t < 512; t += 2){
      step(TrueT{},  t,     a1A, a1B);
      step(TrueT{},  t + 1, a1B, a1A);
    }
  } else {
    for (int t = 0; t < 512; t += 2){
      step(FalseT{}, t,     a1A, a1B);
      step(FalseT{}, t + 1, a1B, a1A);
    }
  }
}

// ---- head: hid = h @ fc1_w^T + fc1_b   (f32)
__global__ void k_head1(const float* __restrict__ hf, const float* __restrict__ w1,
                        const float* __restrict__ b1v, float* __restrict__ hid){
  int b = blockIdx.y;
  int j = blockIdx.x*256 + threadIdx.x;
  if (j >= 500) return;
  float acc = b1v[j];
  const float* hr = hf + b*512;
  const float* wr = w1 + j*512;
  for (int k = 0; k < 512; ++k) acc += hr[k]*wr[k];
  hid[b*500 + j] = acc;
}

// ---- head: logits = hid @ fc2_w^T + fc2_b   (f32 out)
__global__ void k_head2(const float* __restrict__ hid, const float* __restrict__ w2,
                        const float* __restrict__ b2v, float* __restrict__ out){
  int o = blockIdx.x*256 + threadIdx.x;
  if (o >= 640) return;
  int b = o / 5, cls = o % 5;
  float acc = b2v[cls];
  const float* hr = hid + b*500;
  const float* wr = w2 + cls*500;
  for (int j = 0; j < 500; ++j) acc += hr[j]*wr[j];
  out[o] = acc;
}

extern "C" void kernel_launch(void* const* d_in, const int* in_sizes, int n_in,
                              void* d_out, int out_size, void* d_ws, size_t ws_size,
                              hipStream_t stream) {
  const int*   x     = (const int*)d_in[0];
  const float* topic = (const float*)d_in[1];
  const float* h0    = (const float*)d_in[2];
  const float* c0    = (const float*)d_in[3];
  const float* embed = (const float*)d_in[4];
  const float* Wx    = (const float*)d_in[5];
  const float* Wt    = (const float*)d_in[6];
  const float* Wh    = (const float*)d_in[7];
  const float* bias  = (const float*)d_in[8];
  const float* fc1w  = (const float*)d_in[9];
  const float* fc1b  = (const float*)d_in[10];
  const float* fc2w  = (const float*)d_in[11];
  const float* fc2b  = (const float*)d_in[12];

  char* ws = (char*)d_ws;              // total ~5.27 MB
  u16*   WhT = (u16*)(ws + 0);         // 2048*512*2  = 2097152
  u16*   WxT = (u16*)(ws + 2097152);   // 2048*256*2  = 1048576
  float* tb  = (float*)(ws + 3145728); // 128*2048*4  = 1048576
  u16*   hhi = (u16*)(ws + 4194304);   // 2*128*512*2 = 262144
  u16*   hlo = (u16*)(ws + 4456448);   // 262144
  float* hf  = (float*)(ws + 4718592); // 128*512*4   = 262144
  float* hid = (float*)(ws + 4980736); // 128*500*4   = 256000
  u32*   cnt = (u32*)(ws + 5236736);   // 256*4 (group-major, 64B/group)
  u32*   xcd = (u32*)(ws + 5237760);   // 256*4

  k_prep<<<dim3(1536), dim3(32, 8), 0, stream>>>(Wh, Wx, WhT, WxT);
  k_topic<<<dim3(8, 128), dim3(256), 0, stream>>>(topic, Wt, bias, tb);
  k_init<<<dim3(257), dim3(256), 0, stream>>>(h0, hhi, hlo, cnt, xcd);

  k_rnn<<<dim3(256), dim3(256), 0, stream>>>(x, embed, c0, WhT, WxT, tb, hhi, hlo, hf, cnt, xcd);

  k_head1<<<dim3(2, 128), dim3(256), 0, stream>>>(hf, fc1w, fc1b, hid);
  k_head2<<<dim3(3), dim3(256), 0, stream>>>(hid, fc2w, fc2b, (float*)d_out);
}